// Round 12
// baseline (228.256 us; speedup 1.0000x reference)
//
#include <hip/hip_runtime.h>

// VanillaRNN: B=4096, T=1024, I=3, H=32, O=2
// out[b,t,j] = h_t[j];  h_t = tanh(x_t @ W_ih^T + b_ih + b_hh + h_{t-1} @ W_hh^T)
// h_n[b,o] = h_T @ W_fc^T + b_fc
//
// R11 = R10 (wave-internal LDS x-staging ring, 16 lanes/batch, lane owns
// j=2p,2p+1, independent dpp row_ror:m pair rotations, nontemporal f2
// stores, 1 wave/SIMD, launch_bounds(256,1)) + step-body cuts driven by
// the cadence model (wall ~ 4cyc/instr + chain overhang at 1 wave/SIMD):
//  - acc chains split 2x8-deep (a0/a1, b0/b1): chain 96 -> 48 cyc
//  - parallel-half exp2: e = exp2(s.x)*exp2(s.y), s = a0+a1 (pk_add);
//    the two exp2 depend on separate half-chains -> issue in parallel
//  - inf-safe tail kept: th = fma(-2, rcp(e+1), 1)
//  - xp hoisted to per-block precompute (out of the serial region)

typedef float f2 __attribute__((ext_vector_type(2)));

#define RNN_B 4096
#define RNN_T 1024
#define RNN_H 32
#define GROUPS 16             // batches per block (16-lane groups)
#define BLOCK 256
#define DEPTH 4               // steps per staging block
#define NBLK (RNN_T / DEPTH)  // 256

#define SCALE 2.8853900817779268f   // 2*log2(e)

template <int M>
__device__ __forceinline__ f2 rotm(f2 v) {
    // DPP row_ror:M — lane i reads lane (i-M)&15 within its 16-lane row
    f2 r;
    r.x = __int_as_float(__builtin_amdgcn_mov_dpp(__float_as_int(v.x), 0x120 | M, 0xf, 0xf, true));
    r.y = __int_as_float(__builtin_amdgcn_mov_dpp(__float_as_int(v.y), 0x120 | M, 0xf, 0xf, true));
    return r;
}

__global__ __launch_bounds__(BLOCK, 1) void vanilla_rnn_kernel(
    const float* __restrict__ x,     // [B,T,3]
    const float* __restrict__ W_ih,  // [32,3]
    const float* __restrict__ b_ih,  // [32]
    const float* __restrict__ W_hh,  // [32,32]
    const float* __restrict__ b_hh,  // [32]
    const float* __restrict__ W_fc,  // [2,32]
    const float* __restrict__ b_fc,  // [2]
    float* __restrict__ out,         // [B,T,32]
    float* __restrict__ hn_out)      // [B,2]
{
    const int tid = threadIdx.x;
    const int g   = tid >> 4;          // group within block (0..15)
    const int p   = tid & 15;          // pair position within 16-lane row
    const int wv  = tid >> 6;          // wave within block (0..3)
    const int gw  = (tid >> 4) & 3;    // group within wave (0..3)
    const int b   = blockIdx.x * GROUPS + g;
    const int j0  = 2 * p;
    const int j1  = 2 * p + 1;

    __shared__ float hs[GROUPS][32];                  // epilogue only
    __shared__ __align__(16) float xs4[4][2][4][12];  // [wave][slot][gw][12]

    // loader role: lanes 0..47 of each wave stream 1 dword per block
    const int  lw     = tid & 63;
    const bool loader = lw < 48;
    const int  lg     = lw / 12;       // group-in-wave it loads for
    const int  fr     = lw % 12;       // float index within a 12-float block
    const float* lsrc = x + (size_t)(blockIdx.x * GROUPS + wv * 4 + lg) * (RNN_T * 3) + fr;

    // W_hh rows j0,j1 in rotation order (pair q=(p-m)&15), pre-scaled.
    f2 Wa[16], Wb[16];
#pragma unroll
    for (int m = 0; m < 16; ++m) {
        const int q = (p - m) & 15;
        Wa[m].x = W_hh[j0 * 32 + 2 * q]     * SCALE;
        Wa[m].y = W_hh[j0 * 32 + 2 * q + 1] * SCALE;
        Wb[m].x = W_hh[j1 * 32 + 2 * q]     * SCALE;
        Wb[m].y = W_hh[j1 * 32 + 2 * q + 1] * SCALE;
    }

    // x-projection constants (.x -> j0, .y -> j1), pre-scaled
    f2 wi0, wi1, wi2, bs;
    wi0.x = W_ih[j0 * 3 + 0] * SCALE;  wi0.y = W_ih[j1 * 3 + 0] * SCALE;
    wi1.x = W_ih[j0 * 3 + 1] * SCALE;  wi1.y = W_ih[j1 * 3 + 1] * SCALE;
    wi2.x = W_ih[j0 * 3 + 2] * SCALE;  wi2.y = W_ih[j1 * 3 + 2] * SCALE;
    bs.x  = (b_ih[j0] + b_hh[j0]) * SCALE;
    bs.y  = (b_ih[j1] + b_hh[j1]) * SCALE;

    float* ob = out + (size_t)b * RNN_T * RNN_H;

    // prologue: slots <- blocks 0,1; regs <- blocks 2,3 (all wave-internal)
    float xregA = 0.0f, xregB = 0.0f;
    if (loader) {
        const float d0 = lsrc[0];
        const float d1 = lsrc[12];
        xregA = lsrc[24];
        xregB = lsrc[36];
        xs4[wv][0][lg][fr] = d0;
        xs4[wv][1][lg][fr] = d1;
    }

    float hj0 = 0.0f, hj1 = 0.0f;

#define ROT_STEP(M, AA, BB)                                       \
            {                                                     \
                const f2 r = rotm<M>(hp);                         \
                AA = __builtin_elementwise_fma(r, Wa[M], AA);     \
                BB = __builtin_elementwise_fma(r, Wb[M], BB);     \
            }

#define BLOCK_BODY(SLOT, XREG, KB)                                            \
    {                                                                         \
        const float4* sp = reinterpret_cast<const float4*>(&xs4[wv][SLOT][gw][0]); \
        const float4 xq0 = sp[0];                                             \
        const float4 xq1 = sp[1];                                             \
        const float4 xq2 = sp[2];                                             \
        if (loader) {                                                         \
            xs4[wv][SLOT][lg][fr] = XREG;          /* data for KB+2 */        \
            const int kf = ((KB) + 4 < NBLK) ? (KB) + 4 : NBLK - 1;           \
            XREG = lsrc[(size_t)kf * 12];          /* data for KB+4 */        \
        }                                                                     \
        __builtin_amdgcn_sched_barrier(0);                                    \
        const float xv[12] = {xq0.x, xq0.y, xq0.z, xq0.w,                     \
                              xq1.x, xq1.y, xq1.z, xq1.w,                     \
                              xq2.x, xq2.y, xq2.z, xq2.w};                    \
        /* per-block x-projection precompute (h-independent, off the chain) */\
        f2 xp[DEPTH];                                                         \
        _Pragma("unroll")                                                     \
        for (int d = 0; d < DEPTH; ++d) {                                     \
            f2 v = bs;                                                        \
            v = __builtin_elementwise_fma(wi0, (f2){xv[d*3+0], xv[d*3+0]}, v);\
            v = __builtin_elementwise_fma(wi1, (f2){xv[d*3+1], xv[d*3+1]}, v);\
            v = __builtin_elementwise_fma(wi2, (f2){xv[d*3+2], xv[d*3+2]}, v);\
            xp[d] = v;                                                        \
        }                                                                     \
        _Pragma("unroll")                                                     \
        for (int d = 0; d < DEPTH; ++d) {                                     \
            f2 hp; hp.x = hj0; hp.y = hj1;                                    \
            /* 4 independent 8-deep chains */                                 \
            f2 a0, a1, b0, b1;                                                \
            a0.x = xp[d].x; a0.y = 0.0f;                                      \
            b0.x = xp[d].y; b0.y = 0.0f;                                      \
            a1.x = 0.0f;    a1.y = 0.0f;                                      \
            b1.x = 0.0f;    b1.y = 0.0f;                                      \
            a0 = __builtin_elementwise_fma(hp, Wa[0], a0);                    \
            b0 = __builtin_elementwise_fma(hp, Wb[0], b0);                    \
            ROT_STEP(1,  a1, b1)  ROT_STEP(2,  a0, b0)                        \
            ROT_STEP(3,  a1, b1)  ROT_STEP(4,  a0, b0)                        \
            ROT_STEP(5,  a1, b1)  ROT_STEP(6,  a0, b0)                        \
            ROT_STEP(7,  a1, b1)  ROT_STEP(8,  a0, b0)                        \
            ROT_STEP(9,  a1, b1)  ROT_STEP(10, a0, b0)                        \
            ROT_STEP(11, a1, b1)  ROT_STEP(12, a0, b0)                        \
            ROT_STEP(13, a1, b1)  ROT_STEP(14, a0, b0)                        \
            ROT_STEP(15, a1, b1)                                              \
            /* parallel-half exp2: e = exp2(s.x)*exp2(s.y), s = a0+a1 */      \
            const f2 sa = a0 + a1;                                            \
            const f2 sb = b0 + b1;                                            \
            const float ea = exp2f(sa.x) * exp2f(sa.y);                       \
            const float eb = exp2f(sb.x) * exp2f(sb.y);                       \
            const float tha = fmaf(-2.0f, __builtin_amdgcn_rcpf(ea + 1.0f), 1.0f); \
            const float thb = fmaf(-2.0f, __builtin_amdgcn_rcpf(eb + 1.0f), 1.0f); \
            f2 st; st.x = tha; st.y = thb;                                    \
            __builtin_nontemporal_store(                                      \
                st, reinterpret_cast<f2*>(ob + (size_t)((KB) * DEPTH + d) * RNN_H) + p); \
            hj0 = tha; hj1 = thb;                                             \
        }                                                                     \
    }

    for (int k = 0; k < NBLK; k += 2) {
        BLOCK_BODY(0, xregA, k)
        BLOCK_BODY(1, xregB, k + 1)
    }

#undef ROT_STEP
#undef BLOCK_BODY

    // h_n = h_T @ W_fc^T + b_fc  (16-lane group is wave-internal, no barrier)
    hs[g][j0] = hj0;
    hs[g][j1] = hj1;
    if (p < 2) {
        float acc = b_fc[p];
#pragma unroll
        for (int k = 0; k < 32; ++k) acc = fmaf(W_fc[p * 32 + k], hs[g][k], acc);
        hn_out[(size_t)b * 2 + p] = acc;
    }
}

extern "C" void kernel_launch(void* const* d_in, const int* in_sizes, int n_in,
                              void* d_out, int out_size, void* d_ws, size_t ws_size,
                              hipStream_t stream) {
    const float* x    = (const float*)d_in[0];
    const float* W_ih = (const float*)d_in[1];
    const float* b_ih = (const float*)d_in[2];
    const float* W_hh = (const float*)d_in[3];
    const float* b_hh = (const float*)d_in[4];
    const float* W_fc = (const float*)d_in[5];
    const float* b_fc = (const float*)d_in[6];

    float* out    = (float*)d_out;                                   // [B,T,H]
    float* hn_out = out + (size_t)RNN_B * RNN_T * RNN_H;             // [B,2]

    const int grid = RNN_B / GROUPS;  // 256 blocks = 1024 waves = 1/SIMD
    vanilla_rnn_kernel<<<grid, BLOCK, 0, stream>>>(
        x, W_ih, b_ih, W_hh, b_hh, W_fc, b_fc, out, hn_out);
}

// Round 13
// 218.303 us; speedup vs baseline: 1.0456x; 1.0456x over previous
//
#include <hip/hip_runtime.h>

// VanillaRNN: B=4096, T=1024, I=3, H=32, O=2
// out[b,t,j] = h_t[j];  h_t = tanh(x_t @ W_ih^T + b_ih + b_hh + h_{t-1} @ W_hh^T)
// h_n[b,o] = h_T @ W_fc^T + b_fc
//
// R12 = R10 (wave-internal LDS x-staging ring, 16 lanes/batch, lane owns
// j=2p,2p+1, independent dpp row_ror:m pair rotations, exp2-tanh, 1 wave/
// SIMD, launch_bounds(256,1)) + BURST STORES:
//  theory: all designs plateau ~210-230us because the out-write stream is
//  4096 concurrent 128B-per-~500cyc streams -> DRAM row thrash, effective
//  write BW ~2.5 TB/s (= 524MB/211us measured; fillBuffer hits 6.4+).
//  fix: per step ds_write the pair to a 32KB LDS tile; every 16 steps each
//  wave bursts its own 4 batches as 2KB-contiguous-per-batch nontemporal
//  dwordx4 stores (256B coalesced units). Wave-internal -> no barriers.

typedef float f2 __attribute__((ext_vector_type(2)));
typedef float f4 __attribute__((ext_vector_type(4)));

#define RNN_B 4096
#define RNN_T 1024
#define RNN_H 32
#define GROUPS 16             // batches per block (16-lane groups)
#define BLOCK 256
#define DEPTH 4               // steps per staging block
#define NBLK (RNN_T / DEPTH)  // 256
#define SGRP 64               // store groups (16 steps each)

#define SCALE 2.8853900817779268f   // 2*log2(e)

template <int M>
__device__ __forceinline__ f2 rotm(f2 v) {
    // DPP row_ror:M — lane i reads lane (i-M)&15 within its 16-lane row
    f2 r;
    r.x = __int_as_float(__builtin_amdgcn_mov_dpp(__float_as_int(v.x), 0x120 | M, 0xf, 0xf, true));
    r.y = __int_as_float(__builtin_amdgcn_mov_dpp(__float_as_int(v.y), 0x120 | M, 0xf, 0xf, true));
    return r;
}

__global__ __launch_bounds__(BLOCK, 1) void vanilla_rnn_kernel(
    const float* __restrict__ x,     // [B,T,3]
    const float* __restrict__ W_ih,  // [32,3]
    const float* __restrict__ b_ih,  // [32]
    const float* __restrict__ W_hh,  // [32,32]
    const float* __restrict__ b_hh,  // [32]
    const float* __restrict__ W_fc,  // [2,32]
    const float* __restrict__ b_fc,  // [2]
    float* __restrict__ out,         // [B,T,32]
    float* __restrict__ hn_out)      // [B,2]
{
    const int tid = threadIdx.x;
    const int g   = tid >> 4;          // group within block (0..15)
    const int p   = tid & 15;          // pair position within 16-lane row
    const int wv  = tid >> 6;          // wave within block (0..3)
    const int gw  = (tid >> 4) & 3;    // group within wave (0..3)
    const int b   = blockIdx.x * GROUPS + g;
    const int j0  = 2 * p;
    const int j1  = 2 * p + 1;

    __shared__ float hs[GROUPS][32];                  // epilogue only
    __shared__ __align__(16) float xs4[4][2][4][12];  // [wave][slot][gw][12]
    __shared__ __align__(16) float obuf[16][GROUPS][32]; // 16 steps x 16 batches

    // loader role: lanes 0..47 of each wave stream 1 dword per block
    const int  lw     = tid & 63;
    const bool loader = lw < 48;
    const int  lg     = lw / 12;       // group-in-wave it loads for
    const int  fr     = lw % 12;       // float index within a 12-float block
    const float* lsrc = x + (size_t)(blockIdx.x * GROUPS + wv * 4 + lg) * (RNN_T * 3) + fr;

    // W_hh rows j0,j1 in rotation order (pair q=(p-m)&15), pre-scaled.
    f2 Wa[16], Wb[16];
#pragma unroll
    for (int m = 0; m < 16; ++m) {
        const int q = (p - m) & 15;
        Wa[m].x = W_hh[j0 * 32 + 2 * q]     * SCALE;
        Wa[m].y = W_hh[j0 * 32 + 2 * q + 1] * SCALE;
        Wb[m].x = W_hh[j1 * 32 + 2 * q]     * SCALE;
        Wb[m].y = W_hh[j1 * 32 + 2 * q + 1] * SCALE;
    }

    // x-projection constants (.x -> j0, .y -> j1), pre-scaled
    f2 wi0, wi1, wi2, bs;
    wi0.x = W_ih[j0 * 3 + 0] * SCALE;  wi0.y = W_ih[j1 * 3 + 0] * SCALE;
    wi1.x = W_ih[j0 * 3 + 1] * SCALE;  wi1.y = W_ih[j1 * 3 + 1] * SCALE;
    wi2.x = W_ih[j0 * 3 + 2] * SCALE;  wi2.y = W_ih[j1 * 3 + 2] * SCALE;
    bs.x  = (b_ih[j0] + b_hh[j0]) * SCALE;
    bs.y  = (b_ih[j1] + b_hh[j1]) * SCALE;

    float* ob = out + (size_t)b * RNN_T * RNN_H;

    // prologue: slots <- blocks 0,1; regs <- blocks 2,3 (all wave-internal)
    float xregA = 0.0f, xregB = 0.0f;
    if (loader) {
        const float d0 = lsrc[0];
        const float d1 = lsrc[12];
        xregA = lsrc[24];
        xregB = lsrc[36];
        xs4[wv][0][lg][fr] = d0;
        xs4[wv][1][lg][fr] = d1;
    }

    float hj0 = 0.0f, hj1 = 0.0f;

#define ROT_STEP(M)                                               \
            {                                                     \
                const f2 r = rotm<M>(hp);                         \
                acc_a = __builtin_elementwise_fma(r, Wa[M], acc_a);  \
                acc_b = __builtin_elementwise_fma(r, Wb[M], acc_b);  \
            }

#define BLOCK_BODY(SLOT, XREG, KB)                                            \
    {                                                                         \
        const float4* sp = reinterpret_cast<const float4*>(&xs4[wv][SLOT][gw][0]); \
        const float4 xq0 = sp[0];                                             \
        const float4 xq1 = sp[1];                                             \
        const float4 xq2 = sp[2];                                             \
        if (loader) {                                                         \
            xs4[wv][SLOT][lg][fr] = XREG;          /* data for KB+2 */        \
            const int kf = ((KB) + 4 < NBLK) ? (KB) + 4 : NBLK - 1;           \
            XREG = lsrc[(size_t)kf * 12];          /* data for KB+4 */        \
        }                                                                     \
        __builtin_amdgcn_sched_barrier(0);                                    \
        const float xv[12] = {xq0.x, xq0.y, xq0.z, xq0.w,                     \
                              xq1.x, xq1.y, xq1.z, xq1.w,                     \
                              xq2.x, xq2.y, xq2.z, xq2.w};                    \
        _Pragma("unroll")                                                     \
        for (int d = 0; d < DEPTH; ++d) {                                     \
            f2 hp; hp.x = hj0; hp.y = hj1;                                    \
            f2 acc_a, acc_b;                                                  \
            acc_a.x = 0.0f; acc_a.y = 0.0f;                                   \
            acc_b.x = 0.0f; acc_b.y = 0.0f;                                   \
            acc_a = __builtin_elementwise_fma(hp, Wa[0], acc_a);              \
            acc_b = __builtin_elementwise_fma(hp, Wb[0], acc_b);              \
            ROT_STEP(1)  ROT_STEP(2)  ROT_STEP(3)  ROT_STEP(4)                \
            ROT_STEP(5)  ROT_STEP(6)  ROT_STEP(7)  ROT_STEP(8)                \
            ROT_STEP(9)  ROT_STEP(10) ROT_STEP(11) ROT_STEP(12)               \
            ROT_STEP(13) ROT_STEP(14) ROT_STEP(15)                            \
            f2 xpv = bs;                                                      \
            xpv = __builtin_elementwise_fma(wi0, (f2){xv[d*3+0], xv[d*3+0]}, xpv); \
            xpv = __builtin_elementwise_fma(wi1, (f2){xv[d*3+1], xv[d*3+1]}, xpv); \
            xpv = __builtin_elementwise_fma(wi2, (f2){xv[d*3+2], xv[d*3+2]}, xpv); \
            const float ya = acc_a.x + acc_a.y + xpv.x;                       \
            const float yb = acc_b.x + acc_b.y + xpv.y;                       \
            const float tha = fmaf(-2.0f, __builtin_amdgcn_rcpf(exp2f(ya) + 1.0f), 1.0f); \
            const float thb = fmaf(-2.0f, __builtin_amdgcn_rcpf(exp2f(yb) + 1.0f), 1.0f); \
            f2 st; st.x = tha; st.y = thb;                                    \
            *reinterpret_cast<f2*>(&obuf[((KB) & 3) * DEPTH + d][g][p * 2]) = st; \
            hj0 = tha; hj1 = thb;                                             \
        }                                                                     \
    }

    for (int sg = 0; sg < SGRP; ++sg) {
        const int kb = sg * 4;
        BLOCK_BODY(0, xregA, kb + 0)
        BLOCK_BODY(1, xregB, kb + 1)
        BLOCK_BODY(0, xregA, kb + 2)
        BLOCK_BODY(1, xregB, kb + 3)

        // burst: wave writes its own 4 batches, 2KB contiguous per batch,
        // in 256B-coalesced dwordx4 units. Same-wave DS order -> no barrier.
        float* obs = ob + (size_t)sg * 512;   // 16 steps x 32 floats
#pragma unroll
        for (int k2 = 0; k2 < 8; ++k2) {
            const int s = 2 * k2 + (p >> 3);
            const f4 v = *reinterpret_cast<const f4*>(&obuf[s][g][(p & 7) * 4]);
            __builtin_nontemporal_store(v, reinterpret_cast<f4*>(obs) + (k2 * 16 + p));
        }
    }

#undef ROT_STEP
#undef BLOCK_BODY

    // h_n = h_T @ W_fc^T + b_fc  (16-lane group is wave-internal, no barrier)
    hs[g][j0] = hj0;
    hs[g][j1] = hj1;
    if (p < 2) {
        float acc = b_fc[p];
#pragma unroll
        for (int k = 0; k < 32; ++k) acc = fmaf(W_fc[p * 32 + k], hs[g][k], acc);
        hn_out[(size_t)b * 2 + p] = acc;
    }
}

extern "C" void kernel_launch(void* const* d_in, const int* in_sizes, int n_in,
                              void* d_out, int out_size, void* d_ws, size_t ws_size,
                              hipStream_t stream) {
    const float* x    = (const float*)d_in[0];
    const float* W_ih = (const float*)d_in[1];
    const float* b_ih = (const float*)d_in[2];
    const float* W_hh = (const float*)d_in[3];
    const float* b_hh = (const float*)d_in[4];
    const float* W_fc = (const float*)d_in[5];
    const float* b_fc = (const float*)d_in[6];

    float* out    = (float*)d_out;                                   // [B,T,H]
    float* hn_out = out + (size_t)RNN_B * RNN_T * RNN_H;             // [B,2]

    const int grid = RNN_B / GROUPS;  // 256 blocks = 1024 waves = 1/SIMD
    vanilla_rnn_kernel<<<grid, BLOCK, 0, stream>>>(
        x, W_ih, b_ih, W_hh, b_hh, W_fc, b_fc, out, hn_out);
}

// Round 15
// 167.604 us; speedup vs baseline: 1.3619x; 1.3025x over previous
//
#include <hip/hip_runtime.h>

// VanillaRNN: B=4096, T=1024, I=3, H=32, O=2
// out[b,t,j] = h_t[j];  h_t = tanh(x_t @ W_ih^T + b_ih + b_hh + h_{t-1} @ W_hh^T)
// h_n[b,o] = h_T @ W_fc^T + b_fc
//
// R13b = R10 (wave-internal LDS x-staging ring, 16 lanes/batch, lane owns
// j=2p,2p+1, independent dpp row_ror:m rotations, nontemporal f2 stores,
// 1 wave/SIMD, launch_bounds(256,1)) with the rotation ring packed to f16:
//  - rotated value = half2(h[2q], h[2q+1]) in ONE reg -> 15 dpp (was 30)
//  - MAC = v_dot2_f32_f16 (fdot2) with scalar f32 accumulator -> the
//    pair-sum is fused, final .x+.y adds deleted
//  - W_hh pre-scaled by 2*log2e and stored as half2 (f16); h cvt via
//    v_cvt_pkrtz_f16_f32 once per step (bit_cast to h2). Accum stays f32.
// Step body ~64 instr vs R10's ~85. Theory: residual stall scales with
// instruction count (all latency-class theories falsified R7-R12).

typedef float  f2 __attribute__((ext_vector_type(2)));
typedef _Float16 h2 __attribute__((ext_vector_type(2)));

#define RNN_B 4096
#define RNN_T 1024
#define RNN_H 32
#define GROUPS 16             // batches per block (16-lane groups)
#define BLOCK 256
#define DEPTH 4               // steps per staging block
#define NBLK (RNN_T / DEPTH)  // 256

#define SCALE 2.8853900817779268f   // 2*log2(e)

template <int M>
__device__ __forceinline__ h2 rotm16(h2 v) {
    // DPP row_ror:M — lane i reads lane (i-M)&15 within its 16-lane row.
    // One dpp moves both packed f16 halves.
    int iv = __builtin_bit_cast(int, v);
    iv = __builtin_amdgcn_mov_dpp(iv, 0x120 | M, 0xf, 0xf, true);
    return __builtin_bit_cast(h2, iv);
}

__global__ __launch_bounds__(BLOCK, 1) void vanilla_rnn_kernel(
    const float* __restrict__ x,     // [B,T,3]
    const float* __restrict__ W_ih,  // [32,3]
    const float* __restrict__ b_ih,  // [32]
    const float* __restrict__ W_hh,  // [32,32]
    const float* __restrict__ b_hh,  // [32]
    const float* __restrict__ W_fc,  // [2,32]
    const float* __restrict__ b_fc,  // [2]
    float* __restrict__ out,         // [B,T,32]
    float* __restrict__ hn_out)      // [B,2]
{
    const int tid = threadIdx.x;
    const int g   = tid >> 4;          // group within block (0..15)
    const int p   = tid & 15;          // pair position within 16-lane row
    const int wv  = tid >> 6;          // wave within block (0..3)
    const int gw  = (tid >> 4) & 3;    // group within wave (0..3)
    const int b   = blockIdx.x * GROUPS + g;
    const int j0  = 2 * p;
    const int j1  = 2 * p + 1;

    __shared__ float hs[GROUPS][32];                  // epilogue only
    __shared__ __align__(16) float xs4[4][2][4][12];  // [wave][slot][gw][12]

    // loader role: lanes 0..47 of each wave stream 1 dword per block
    const int  lw     = tid & 63;
    const bool loader = lw < 48;
    const int  lg     = lw / 12;       // group-in-wave it loads for
    const int  fr     = lw % 12;       // float index within a 12-float block
    const float* lsrc = x + (size_t)(blockIdx.x * GROUPS + wv * 4 + lg) * (RNN_T * 3) + fr;

    // W_hh rows j0,j1 in rotation order (pair q=(p-m)&15), pre-scaled, f16.
    h2 Wa[16], Wb[16];
#pragma unroll
    for (int m = 0; m < 16; ++m) {
        const int q = (p - m) & 15;
        Wa[m].x = (_Float16)(W_hh[j0 * 32 + 2 * q]     * SCALE);
        Wa[m].y = (_Float16)(W_hh[j0 * 32 + 2 * q + 1] * SCALE);
        Wb[m].x = (_Float16)(W_hh[j1 * 32 + 2 * q]     * SCALE);
        Wb[m].y = (_Float16)(W_hh[j1 * 32 + 2 * q + 1] * SCALE);
    }

    // x-projection constants (.x -> j0, .y -> j1), pre-scaled (f32)
    f2 wi0, wi1, wi2, bs;
    wi0.x = W_ih[j0 * 3 + 0] * SCALE;  wi0.y = W_ih[j1 * 3 + 0] * SCALE;
    wi1.x = W_ih[j0 * 3 + 1] * SCALE;  wi1.y = W_ih[j1 * 3 + 1] * SCALE;
    wi2.x = W_ih[j0 * 3 + 2] * SCALE;  wi2.y = W_ih[j1 * 3 + 2] * SCALE;
    bs.x  = (b_ih[j0] + b_hh[j0]) * SCALE;
    bs.y  = (b_ih[j1] + b_hh[j1]) * SCALE;

    float* ob = out + (size_t)b * RNN_T * RNN_H;

    // prologue: slots <- blocks 0,1; regs <- blocks 2,3 (all wave-internal)
    float xregA = 0.0f, xregB = 0.0f;
    if (loader) {
        const float d0 = lsrc[0];
        const float d1 = lsrc[12];
        xregA = lsrc[24];
        xregB = lsrc[36];
        xs4[wv][0][lg][fr] = d0;
        xs4[wv][1][lg][fr] = d1;
    }

    float hj0 = 0.0f, hj1 = 0.0f;
    h2 hp0 = (h2){(_Float16)0.0f, (_Float16)0.0f};   // packed (h[j0],h[j1])

#define ROT_STEP(M)                                                \
            {                                                      \
                const h2 r = rotm16<M>(hp0);                       \
                a0 = __builtin_amdgcn_fdot2(r, Wa[M], a0, false);  \
                b0 = __builtin_amdgcn_fdot2(r, Wb[M], b0, false);  \
            }

#define BLOCK_BODY(SLOT, XREG, KB)                                            \
    {                                                                         \
        const float4* sp = reinterpret_cast<const float4*>(&xs4[wv][SLOT][gw][0]); \
        const float4 xq0 = sp[0];                                             \
        const float4 xq1 = sp[1];                                             \
        const float4 xq2 = sp[2];                                             \
        if (loader) {                                                         \
            xs4[wv][SLOT][lg][fr] = XREG;          /* data for KB+2 */        \
            const int kf = ((KB) + 4 < NBLK) ? (KB) + 4 : NBLK - 1;           \
            XREG = lsrc[(size_t)kf * 12];          /* data for KB+4 */        \
        }                                                                     \
        __builtin_amdgcn_sched_barrier(0);                                    \
        const float xv[12] = {xq0.x, xq0.y, xq0.z, xq0.w,                     \
                              xq1.x, xq1.y, xq1.z, xq1.w,                     \
                              xq2.x, xq2.y, xq2.z, xq2.w};                    \
        /* per-block x-projection precompute (h-independent) */               \
        f2 xp[DEPTH];                                                         \
        _Pragma("unroll")                                                     \
        for (int d = 0; d < DEPTH; ++d) {                                     \
            f2 v = bs;                                                        \
            v = __builtin_elementwise_fma(wi0, (f2){xv[d*3+0], xv[d*3+0]}, v);\
            v = __builtin_elementwise_fma(wi1, (f2){xv[d*3+1], xv[d*3+1]}, v);\
            v = __builtin_elementwise_fma(wi2, (f2){xv[d*3+2], xv[d*3+2]}, v);\
            xp[d] = v;                                                        \
        }                                                                     \
        _Pragma("unroll")                                                     \
        for (int d = 0; d < DEPTH; ++d) {                                     \
            float a0 = xp[d].x;                                               \
            float b0 = xp[d].y;                                               \
            a0 = __builtin_amdgcn_fdot2(hp0, Wa[0], a0, false);               \
            b0 = __builtin_amdgcn_fdot2(hp0, Wb[0], b0, false);               \
            ROT_STEP(1)  ROT_STEP(2)  ROT_STEP(3)  ROT_STEP(4)                \
            ROT_STEP(5)  ROT_STEP(6)  ROT_STEP(7)  ROT_STEP(8)                \
            ROT_STEP(9)  ROT_STEP(10) ROT_STEP(11) ROT_STEP(12)               \
            ROT_STEP(13) ROT_STEP(14) ROT_STEP(15)                            \
            /* tanh(z) = 1 - 2/(exp2(2*log2e*z)+1); inf-safe */               \
            const float tha = fmaf(-2.0f, __builtin_amdgcn_rcpf(exp2f(a0) + 1.0f), 1.0f); \
            const float thb = fmaf(-2.0f, __builtin_amdgcn_rcpf(exp2f(b0) + 1.0f), 1.0f); \
            f2 st; st.x = tha; st.y = thb;                                    \
            __builtin_nontemporal_store(                                      \
                st, reinterpret_cast<f2*>(ob + (size_t)((KB) * DEPTH + d) * RNN_H) + p); \
            hp0 = __builtin_bit_cast(h2, __builtin_amdgcn_cvt_pkrtz(tha, thb)); \
            hj0 = tha; hj1 = thb;                                             \
        }                                                                     \
    }

    for (int k = 0; k < NBLK; k += 2) {
        BLOCK_BODY(0, xregA, k)
        BLOCK_BODY(1, xregB, k + 1)
    }

#undef ROT_STEP
#undef BLOCK_BODY

    // h_n = h_T @ W_fc^T + b_fc  (16-lane group is wave-internal, no barrier)
    hs[g][j0] = hj0;
    hs[g][j1] = hj1;
    if (p < 2) {
        float acc = b_fc[p];
#pragma unroll
        for (int k = 0; k < 32; ++k) acc = fmaf(W_fc[p * 32 + k], hs[g][k], acc);
        hn_out[(size_t)b * 2 + p] = acc;
    }
}

extern "C" void kernel_launch(void* const* d_in, const int* in_sizes, int n_in,
                              void* d_out, int out_size, void* d_ws, size_t ws_size,
                              hipStream_t stream) {
    const float* x    = (const float*)d_in[0];
    const float* W_ih = (const float*)d_in[1];
    const float* b_ih = (const float*)d_in[2];
    const float* W_hh = (const float*)d_in[3];
    const float* b_hh = (const float*)d_in[4];
    const float* W_fc = (const float*)d_in[5];
    const float* b_fc = (const float*)d_in[6];

    float* out    = (float*)d_out;                                   // [B,T,H]
    float* hn_out = out + (size_t)RNN_B * RNN_T * RNN_H;             // [B,2]

    const int grid = RNN_B / GROUPS;  // 256 blocks = 1024 waves = 1/SIMD
    vanilla_rnn_kernel<<<grid, BLOCK, 0, stream>>>(
        x, W_ih, b_ih, W_hh, b_hh, W_fc, b_fc, out, hn_out);
}